// Round 2
// baseline (447.216 us; speedup 1.0000x reference)
//
#include <hip/hip_runtime.h>
#include <hip/hip_bf16.h>

// QuantizedLinear: out[64,8192] = x[64,8192] @ (alpha * ternary(W))^T + bias
// W is [O=8192, I=8192] fp32 row-major. Ternary {-1,0,+1} exact in bf16; alpha
// applied fp32 in epilogue; only x is rounded to bf16.
//
// Single-pass design: 512 blocks x 16 n-cols. Within a block, the 4 waves
// split K 4-ways (2048 each) -> no cross-block K-split -> no atomics, no
// output pre-seeding. Partial 64x16 tiles are summed through a 16 KB LDS
// reduction, then stored once with bias fused. W is loaded fp32 directly in
// MFMA B-fragment layout, ternarized in-register to bf16. X comes from the
// bf16 workspace (L2-resident, 1 MB). No barriers in the K-loop.

typedef __attribute__((ext_vector_type(8))) short short8;   // 8 bf16 = 4 VGPRs
typedef __attribute__((ext_vector_type(4))) float floatx4;  // MFMA acc

#define B_DIM 64
#define K_DIM 8192
#define O_DIM 8192
#define BN 16                      // n-cols per block
#define NWAVE 4                    // waves, each owns K/4
#define KW (K_DIM / NWAVE)         // 2048 k per wave
#define KSTEPS (KW / 32)           // 64 MFMA k-steps of K=32

// ---- prep: x fp32 -> bf16 workspace (8 elems/thread, vectorized) ----
__global__ __launch_bounds__(256) void prep_kernel(
    const float* __restrict__ x, __hip_bfloat16* __restrict__ xbf) {
  int idx = (blockIdx.x * 256 + threadIdx.x) * 8;
  float4 v0 = *(const float4*)(x + idx);
  float4 v1 = *(const float4*)(x + idx + 4);
  __hip_bfloat16 h[8];
  h[0] = __float2bfloat16(v0.x); h[1] = __float2bfloat16(v0.y);
  h[2] = __float2bfloat16(v0.z); h[3] = __float2bfloat16(v0.w);
  h[4] = __float2bfloat16(v1.x); h[5] = __float2bfloat16(v1.y);
  h[6] = __float2bfloat16(v1.z); h[7] = __float2bfloat16(v1.w);
  *(short8*)&xbf[idx] = *(const short8*)h;
}

// ---- main GEMM: 512 blocks (one 16-col n-tile each), 256 threads, no LDS staging ----
__global__ __launch_bounds__(256, 2) void gemm_kernel(
    const float* __restrict__ w, const unsigned short* __restrict__ xbf,
    const float* __restrict__ alpha, const float* __restrict__ bias,
    float* __restrict__ out) {
  __shared__ __align__(16) float red[NWAVE][4][64][4];   // 16 KB k-reduction buffer

  const int tid = threadIdx.x;
  const int n0 = blockIdx.x * BN;

  const int wv  = tid >> 6;    // wave 0..3 -> k-slice
  const int ln  = tid & 63;
  const int lhi = ln >> 4;     // 0..3 -> k-subgroup of 8
  const int llo = ln & 15;     // fragment row (n within tile / m within A)

  // This lane's W row (output col) -- B-frag layout row = lane&15.
  const int nrow = n0 + llo;
  const float av  = alpha[nrow];
  const float thr = 0.5f * (av + 1e-8f);   // |w| > 0.5*(alpha+eps) -> +/-1

  // W: 8 contiguous fp32 at k = wv*KW + lhi*8 + kt*32 (exact B-frag map).
  const float* wp = w + (size_t)nrow * K_DIM + (size_t)(wv * KW + lhi * 8);
  // X: A-frag row = mt*16 + llo, same k (16 B contiguous bf16).
  const unsigned short* xp = xbf + (size_t)llo * K_DIM + (size_t)(wv * KW + lhi * 8);

  floatx4 acc[4];
#pragma unroll
  for (int i = 0; i < 4; ++i) acc[i] = (floatx4){0.f, 0.f, 0.f, 0.f};

  auto tern = [&](float v) -> short {
    // +1 -> 0x3F80, -1 -> 0xBF80, 0 -> 0 (bf16 bit patterns)
    return v > thr ? (short)0x3F80
                   : (v < -thr ? (short)(unsigned short)0xBF80 : (short)0);
  };

#pragma unroll 4
  for (int kt = 0; kt < KSTEPS; ++kt) {
    const float* p = wp + kt * 32;
    float4 w0 = *(const float4*)(p);
    float4 w1 = *(const float4*)(p + 4);

    const unsigned short* q = xp + kt * 32;
    short8 a0 = *(const short8*)(const void*)(q);
    short8 a1 = *(const short8*)(const void*)(q + 16 * (size_t)K_DIM);
    short8 a2 = *(const short8*)(const void*)(q + 32 * (size_t)K_DIM);
    short8 a3 = *(const short8*)(const void*)(q + 48 * (size_t)K_DIM);

    short8 b;
    b[0] = tern(w0.x); b[1] = tern(w0.y); b[2] = tern(w0.z); b[3] = tern(w0.w);
    b[4] = tern(w1.x); b[5] = tern(w1.y); b[6] = tern(w1.z); b[7] = tern(w1.w);

    acc[0] = __builtin_amdgcn_mfma_f32_16x16x32_bf16(a0, b, acc[0], 0, 0, 0);
    acc[1] = __builtin_amdgcn_mfma_f32_16x16x32_bf16(a1, b, acc[1], 0, 0, 0);
    acc[2] = __builtin_amdgcn_mfma_f32_16x16x32_bf16(a2, b, acc[2], 0, 0, 0);
    acc[3] = __builtin_amdgcn_mfma_f32_16x16x32_bf16(a3, b, acc[3], 0, 0, 0);
  }

  // ---- cross-wave k-reduction: each wave parks its 4 partial frags ----
#pragma unroll
  for (int mt = 0; mt < 4; ++mt)
    *(floatx4*)&red[wv][mt][ln][0] = acc[mt];
  __syncthreads();

  // Wave wv reduces m-block mt = wv across the 4 k-slices and stores.
  floatx4 s = *(const floatx4*)&red[0][wv][ln][0];
#pragma unroll
  for (int w2 = 1; w2 < NWAVE; ++w2) {
    floatx4 t = *(const floatx4*)&red[w2][wv][ln][0];
    s[0] += t[0]; s[1] += t[1]; s[2] += t[2]; s[3] += t[3];
  }

  // C/D layout: col = lane&15 (n), row = (lane>>4)*4 + reg (m); fp32 alpha+bias
  const float bv = bias[nrow];
  const int mbase = wv * 16 + lhi * 4;
#pragma unroll
  for (int r = 0; r < 4; ++r) {
    out[(size_t)(mbase + r) * O_DIM + nrow] = s[r] * av + bv;
  }
}

extern "C" void kernel_launch(void* const* d_in, const int* in_sizes, int n_in,
                              void* d_out, int out_size, void* d_ws, size_t ws_size,
                              hipStream_t stream) {
  const float* x     = (const float*)d_in[0];  // [64, 8192]
  const float* w     = (const float*)d_in[1];  // [8192, 8192]
  const float* alpha = (const float*)d_in[2];  // [8192, 1]
  const float* bias  = (const float*)d_in[3];  // [8192]
  float* out = (float*)d_out;                  // [64, 8192]
  __hip_bfloat16* xbf = (__hip_bfloat16*)d_ws; // 1 MB scratch

  prep_kernel<<<(B_DIM * K_DIM) / (256 * 8), 256, 0, stream>>>(x, xbf);
  gemm_kernel<<<O_DIM / BN, 256, 0, stream>>>(
      w, (const unsigned short*)xbf, alpha, bias, out);
}

// Round 3
// 412.136 us; speedup vs baseline: 1.0851x; 1.0851x over previous
//
#include <hip/hip_runtime.h>
#include <hip/hip_bf16.h>

// QuantizedLinear: out[64,8192] = x[64,8192] @ (alpha * ternary(W))^T + bias
// W is [O=8192, I=8192] fp32 row-major. Ternary {-1,0,+1} exact in bf16; alpha
// applied fp32 in epilogue; only x is rounded to bf16.
//
// m97-style staged streaming: W tiles (64 rows x 64 k, fp32, 16 KB) and X
// tiles (64 m x 64 k, bf16, 8 KB) are staged via async global_load_lds
// width-16 -- every staging instruction is a contiguous 1 KB wave segment
// (fixes the 16-segment/instr address divergence that left rounds 0-2
// latency-bound at ~1.5 TB/s demand). Double-buffered LDS, one barrier per
// tile. Ternarize fp32->bf16 on the LDS->fragment read. LDS reads use the
// measured byte ^= ((row&7)<<4) XOR swizzle, applied on BOTH the pre-swizzled
// global source and the ds_read address (linear DMA dest).

typedef __attribute__((ext_vector_type(8))) short short8;   // 8 bf16 = 4 VGPRs
typedef __attribute__((ext_vector_type(4))) float floatx4;  // MFMA acc

#define B_DIM 64
#define K_DIM 8192
#define O_DIM 8192
#define BN 64                      // W rows (output cols) per block
#define BK 64                      // k per tile
#define KSPLIT 8
#define KCHUNK (K_DIM / KSPLIT)    // 1024 k per block
#define NT (KCHUNK / BK)           // 16 tiles

__device__ __forceinline__ void gload_lds16(const void* g, void* l) {
  __builtin_amdgcn_global_load_lds(
      (const __attribute__((address_space(1))) void*)g,
      (__attribute__((address_space(3))) void*)l, 16, 0, 0);
}

// ---- prep: x fp32 -> bf16 workspace (vectorized); out = bias broadcast ----
__global__ __launch_bounds__(256) void prep_kernel(
    const float* __restrict__ x, const float* __restrict__ bias,
    __hip_bfloat16* __restrict__ xbf, float* __restrict__ out) {
  int idx = (blockIdx.x * 256 + threadIdx.x) * 8;
  float4 v0 = *(const float4*)(x + idx);
  float4 v1 = *(const float4*)(x + idx + 4);
  __hip_bfloat16 h[8];
  h[0] = __float2bfloat16(v0.x); h[1] = __float2bfloat16(v0.y);
  h[2] = __float2bfloat16(v0.z); h[3] = __float2bfloat16(v0.w);
  h[4] = __float2bfloat16(v1.x); h[5] = __float2bfloat16(v1.y);
  h[6] = __float2bfloat16(v1.z); h[7] = __float2bfloat16(v1.w);
  *(short8*)&xbf[idx] = *(const short8*)h;
  int bidx = idx & (O_DIM - 1);
  *(float4*)(out + idx)     = *(const float4*)(bias + bidx);
  *(float4*)(out + idx + 4) = *(const float4*)(bias + bidx + 4);
}

// ---- main GEMM: 1024 blocks (128 n-tiles x 8 k-slices), 256 threads ----
__global__ __launch_bounds__(256, 3) void gemm_kernel(
    const float* __restrict__ w, const unsigned short* __restrict__ xbf,
    const float* __restrict__ alpha, float* __restrict__ out) {
  __shared__ __align__(16) float Ws[2][BN][BK];           // 32 KB
  __shared__ __align__(16) unsigned short Xs[2][B_DIM][BK]; // 16 KB

  const int tid = threadIdx.x;
  const int nt = blockIdx.x & 127;   // n-tile (fast dim)
  const int ks = blockIdx.x >> 7;    // k-slice 0..7
  const int n0 = nt * BN;
  const int k0 = ks * KCHUNK;

  const int wv  = tid >> 6;    // wave 0..3
  const int ln  = tid & 63;
  const int lhi = ln >> 4;     // 0..3 -> k-subgroup of 8
  const int llo = ln & 15;     // fragment row

  // Compute-side lane identity: W row (output col) = wv*16 + llo.
  const int nrow = n0 + wv * 16 + llo;
  const float av  = alpha[nrow];
  const float thr = 0.5f * (av + 1e-8f);   // |w| > 0.5*(alpha+eps) -> +/-1
  const int sw = (llo & 7) << 4;           // read-side XOR swizzle (bytes)

  floatx4 acc[4];
#pragma unroll
  for (int i = 0; i < 4; ++i) acc[i] = (floatx4){0.f, 0.f, 0.f, 0.f};

  auto tern = [&](float v) -> short {
    return v > thr ? (short)0x3F80
                   : (v < -thr ? (short)(unsigned short)0xBF80 : (short)0);
  };

  // ---- async staging: every instruction is a contiguous 1 KB wave segment ----
  auto stage = [&](int buf, int kt) {
    const size_t kb = (size_t)(k0 + kt * BK);
    // W: 4 instrs/wave, 4 rows x 256 B each; source pre-swizzled within row.
#pragma unroll
    for (int j = 0; j < 4; ++j) {
      const int r0  = wv * 16 + j * 4;
      const int row = r0 + (ln >> 4);
      const char* src = (const char*)w
          + ((size_t)(n0 + row) * K_DIM + kb) * 4
          + (((ln & 15) * 16) ^ ((row & 7) << 4));
      gload_lds16(src, &Ws[buf][r0][0]);
    }
    // X: 2 instrs/wave, 8 rows x 128 B each; source pre-swizzled within row.
#pragma unroll
    for (int j = 0; j < 2; ++j) {
      const int r0  = wv * 16 + j * 8;
      const int row = r0 + (ln >> 3);
      const char* src = (const char*)xbf
          + ((size_t)row * K_DIM + kb) * 2
          + (((ln & 7) * 16) ^ ((row & 7) << 4));
      gload_lds16(src, &Xs[buf][r0][0]);
    }
  };

  auto compute = [&](int buf) {
    const char* wrow = (const char*)&Ws[buf][wv * 16 + llo][0];
#pragma unroll
    for (int kk = 0; kk < 2; ++kk) {
      const int cW = kk * 128 + lhi * 32;
      float4 f0 = *(const float4*)(wrow + ((cW)      ^ sw));
      float4 f1 = *(const float4*)(wrow + ((cW + 16) ^ sw));
      short8 b;
      b[0] = tern(f0.x); b[1] = tern(f0.y); b[2] = tern(f0.z); b[3] = tern(f0.w);
      b[4] = tern(f1.x); b[5] = tern(f1.y); b[6] = tern(f1.z); b[7] = tern(f1.w);
      const int cX = kk * 64 + lhi * 16;
#pragma unroll
      for (int mt = 0; mt < 4; ++mt) {
        short8 a = *(const short8*)((const char*)&Xs[buf][mt * 16 + llo][0]
                                    + (cX ^ sw));
        acc[mt] = __builtin_amdgcn_mfma_f32_16x16x32_bf16(a, b, acc[mt], 0, 0, 0);
      }
    }
  };

  stage(0, 0);
  __syncthreads();                 // drains vmcnt -> tile 0 resident
  int buf = 0;
  for (int kt = 0; kt < NT; ++kt) {
    if (kt + 1 < NT) stage(buf ^ 1, kt + 1);  // async, overlaps compute
    compute(buf);
    __syncthreads();               // all reads of buf done + buf^1 landed
    buf ^= 1;
  }

  // epilogue: C/D layout col=lane&15 (n), row=(lane>>4)*4+reg (m); fp32 alpha
#pragma unroll
  for (int mt = 0; mt < 4; ++mt) {
    const int m = mt * 16 + lhi * 4;
#pragma unroll
    for (int r = 0; r < 4; ++r) {
      atomicAdd(&out[(size_t)(m + r) * O_DIM + nrow], acc[mt][r] * av);
    }
  }
}

extern "C" void kernel_launch(void* const* d_in, const int* in_sizes, int n_in,
                              void* d_out, int out_size, void* d_ws, size_t ws_size,
                              hipStream_t stream) {
  const float* x     = (const float*)d_in[0];  // [64, 8192]
  const float* w     = (const float*)d_in[1];  // [8192, 8192]
  const float* alpha = (const float*)d_in[2];  // [8192, 1]
  const float* bias  = (const float*)d_in[3];  // [8192]
  float* out = (float*)d_out;                  // [64, 8192]
  __hip_bfloat16* xbf = (__hip_bfloat16*)d_ws; // 1 MB scratch

  prep_kernel<<<(B_DIM * K_DIM) / (256 * 8), 256, 0, stream>>>(x, bias, xbf, out);
  gemm_kernel<<<(O_DIM / BN) * KSPLIT, 256, 0, stream>>>(
      w, (const unsigned short*)xbf, alpha, out);
}